// Round 10
// baseline (165.574 us; speedup 1.0000x reference)
//
#include <hip/hip_runtime.h>
#include <math.h>

#define BB 4
#define NN 8192
#define CC 256
#define OUTC 256
#define EE 262144
#define MROWS (BB*NN)   /* 32768 */
#define CAP 96          /* adjacency bucket capacity; deg ~ Poisson(32) */

typedef __attribute__((ext_vector_type(8))) short short8;
typedef __attribute__((ext_vector_type(4))) short s16x4;
typedef __attribute__((ext_vector_type(4))) float f32x4;
typedef __attribute__((ext_vector_type(2))) unsigned int u32x2;

__device__ inline unsigned short f2bf(float f) {
    union { float f; unsigned u; } a; a.f = f;
    unsigned u = a.u;
    u += 0x7fffu + ((u >> 16) & 1u);   // RNE
    return (unsigned short)(u >> 16);
}
__device__ inline float bf2f(unsigned short h) {
    union { unsigned u; float f; } a; a.u = ((unsigned)h) << 16;
    return a.f;
}
__device__ inline float asf(unsigned u) {
    union { unsigned u; float f; } a; a.u = u;
    return a.f;
}
__device__ inline float gelu1(float v) {
    // tanh-form GeLU; |err| < ~1e-3, far below bf16 noise (threshold 0.12)
    float t = v * (0.7978845608f + 0.0356774081f * v * v);
    float e = __expf(2.0f * t);
    float th = 1.0f - 2.0f / (e + 1.0f);
    return 0.5f * v * (1.0f + th);
}

// ---------------- kernel 1: W -> fragment-order swizzle + cnt zero ----------------

__global__ __launch_bounds__(256) void prep_w(const float* __restrict__ Ws,
                                              const float* __restrict__ Wn,
                                              unsigned short* __restrict__ Wt2,
                                              int* __restrict__ cnt) {
    int bi = blockIdx.x;
    int tid = threadIdx.x;
    if (bi >= 32) {
        cnt[(bi - 32) * 256 + tid] = 0;
        return;
    }
    __shared__ float tile[64][65];
    int kt = bi >> 3, nt = bi & 7;          // kt 0..3, nt 0..7
    int k0 = kt * 64, n0 = nt * 64;
    const float* W = (n0 < 256) ? Ws : Wn;
    int ncol = n0 & 255;
#pragma unroll
    for (int p = 0; p < 4; p++) {
        int krow = p * 16 + (tid >> 4);
        int col = (tid & 15) * 4;
        float4 v = *(const float4*)&W[(size_t)(k0 + krow) * 256 + ncol + col];
        tile[krow][col + 0] = v.x;
        tile[krow][col + 1] = v.y;
        tile[krow][col + 2] = v.z;
        tile[krow][col + 3] = v.w;
    }
    __syncthreads();
#pragma unroll
    for (int e = 0; e < 2; e++) {
        int idx = e * 256 + tid;            // 0..511
        int lane = idx & 63;
        int ni = (idx >> 6) & 3;
        int kkl = idx >> 8;                 // 0..1
        int kk = kt * 2 + kkl;
        int qrow = lane >> 4, fr = lane & 15;
        short8 t;
#pragma unroll
        for (int j = 0; j < 8; j++)
            t[j] = (short)f2bf(tile[kkl * 32 + qrow * 8 + j][ni * 16 + fr]);
        *(short8*)&Wt2[(size_t)(((nt * 8 + kk) * 4 + ni) * 512) + lane * 8] = t;
    }
}

// ---------------- kernel 2: edge bucket fill (blocks 0..255) + MFMA GEMM (256..767) --

#define APAD 8
#define ALD (256 + APAD)

__global__ __launch_bounds__(256, 2) void gemm_fill(const float* __restrict__ X,
                                                    const unsigned short* __restrict__ Wt2,
                                                    unsigned short* __restrict__ Zb,
                                                    unsigned short* __restrict__ U,
                                                    const int* __restrict__ ei,
                                                    int* __restrict__ cnt,
                                                    unsigned short* __restrict__ adjb) {
    __shared__ unsigned short sA[64 * ALD];
    int bi = blockIdx.x;
    int tid = threadIdx.x;

    if (bi < 256) {   // ---- edge bucket fill (leads the grid; overlaps GEMM) ----
        int e = bi * 256 + tid;
        for (; e < EE; e += 256 * 256) {
            int s = ei[e] & (NN - 1);
            int d = ei[EE + e] & (NN - 1);
            int slot = atomicAdd(&cnt[s], 1);
            if (slot < CAP) adjb[(size_t)s * CAP + slot] = (unsigned short)d;
        }
        return;
    }

    int wave = tid >> 6, lane = tid & 63;
    int row0 = (bi - 256) * 64;
    int qrow = lane >> 4;
    int fr = lane & 15;

    // stage A stripe (64x256 fp32 -> bf16), lane-contiguous: 16 req/instr
#pragma unroll
    for (int q = 0; q < 16; q++) {
        int f = q * 1024 + tid * 4;         // flat elem in 64x256
        int rr = f >> 8, k0 = f & 255;
        float4 v = *(const float4*)&X[(size_t)(row0 + rr) * 256 + k0];
        s16x4 t;
        t[0] = (short)f2bf(v.x); t[1] = (short)f2bf(v.y);
        t[2] = (short)f2bf(v.z); t[3] = (short)f2bf(v.w);
        *(s16x4*)&sA[rr * ALD + k0] = t;
    }
    __syncthreads();   // the only barrier

#pragma unroll 1
    for (int sp = 0; sp < 2; sp++) {
        int colbase = wave * 128 + sp * 64;         // global col in [0,512)
        int ct = wave * 2 + sp;                     // 64-col tile id
        const unsigned short* Bp = Wt2 + (size_t)ct * 8 * 4 * 512 + lane * 8;
        // frag (kk, ni) at Bp + (kk*4+ni)*512

        f32x4 acc[4][4];   // [ni][mi]
#pragma unroll
        for (int ni = 0; ni < 4; ni++)
#pragma unroll
            for (int mi = 0; mi < 4; mi++) acc[ni][mi] = (f32x4)0.0f;

        short8 bbuf[3][4];
#pragma unroll
        for (int ni = 0; ni < 4; ni++) {
            bbuf[0][ni] = *(const short8*)&Bp[(size_t)(0 * 4 + ni) * 512];
            bbuf[1][ni] = *(const short8*)&Bp[(size_t)(1 * 4 + ni) * 512];
        }

#pragma unroll
        for (int kk = 0; kk < 8; kk++) {
            if (kk < 6) {
#pragma unroll
                for (int ni = 0; ni < 4; ni++)
                    bbuf[(kk + 2) % 3][ni] =
                        *(const short8*)&Bp[(size_t)((kk + 2) * 4 + ni) * 512];
            }
            int ak = kk * 32 + qrow * 8;
            short8 af[4];
#pragma unroll
            for (int mi = 0; mi < 4; mi++)
                af[mi] = *(const short8*)&sA[(mi * 16 + fr) * ALD + ak];
            // OPERAND-SWAPPED: D' = (Wt-frag as A-op) x (X-frag as B-op) = C^T tile
#pragma unroll
            for (int ni = 0; ni < 4; ni++)
#pragma unroll
                for (int mi = 0; mi < 4; mi++)
                    acc[ni][mi] = __builtin_amdgcn_mfma_f32_16x16x32_bf16(
                        bbuf[kk % 3][ni], af[mi], acc[ni][mi], 0, 0, 0);
        }

        // epilogue: lane holds C[row = row0+mi*16+fr][cols colbase+ni*16+qrow*4 .. +3]
#pragma unroll
        for (int mi = 0; mi < 4; mi++) {
            size_t row = (size_t)(row0 + mi * 16 + fr);
#pragma unroll
            for (int ni = 0; ni < 4; ni++) {
                int col = colbase + ni * 16 + qrow * 4;
                s16x4 t;
                t[0] = (short)f2bf(acc[ni][mi][0]);
                t[1] = (short)f2bf(acc[ni][mi][1]);
                t[2] = (short)f2bf(acc[ni][mi][2]);
                t[3] = (short)f2bf(acc[ni][mi][3]);
                if (colbase < 256) *(s16x4*)&Zb[row * 512 + 256 + col] = t;  // d_out row tail
                else               *(s16x4*)&U[row * 256 + (col - 256)] = t;
            }
        }
    }
}

// ---------------- kernel 3: aggregate + bias + GeLU -------------------------------
// r5-r7 model: gather chain is SERIALIZED per wave (~35 x ~700cy), hidden only by
// 32 waves/CU; concurrency tweaks (r6/r7) don't move it -> latency source is L2
// MISSES: U[b] gather set = 4MB/XCD = exactly L2 size, evicted by Zb/Out streams.
// Fix: CHANNEL-SPLIT. Each wave = 2 rows x 128 cols (lanes 0-31 row A, 32-63 row B,
// 4 bf16 cols/lane); grid high bit = column half, so half-0 blocks dispatch+retire
// before half-1 -> per-phase gather set 2MB/XCD -> L2-resident (~300cy). Same total
// bytes, same instr count (one 64-lane load = two 256B segments = 8 lines), results
// bitwise identical. Indices = per-lane vector loads (2 addrs/wave, L1 broadcast).

__global__ __launch_bounds__(256) void agg_gelu(const unsigned short* __restrict__ U,
                                                const int* __restrict__ cnt,
                                                const unsigned short* __restrict__ adjb,
                                                const float* __restrict__ bs,
                                                const float* __restrict__ bn,
                                                float* __restrict__ Out) {
    int blk = blockIdx.x;
    int half = blk >> 12;                 // blocks 0..4095 = cols 0..127 (dispatch 1st)
    int blk12 = blk & 4095;
    int r = blk12 & 7;                    // XCD pin; b = r&3 (2 XCDs per batch)
    int b = r & 3;
    int grp = ((r >> 2) << 9) + (blk12 >> 3);   // 0..1023
    int wave = threadIdx.x >> 6;
    int lane = threadIdx.x & 63;
    int sub = lane >> 5;                  // 0: row A, 1: row B
    int l5 = lane & 31;
    int i = grp * 8 + wave * 2 + sub;     // 0..8191, each (i,half) exactly once
    int cu = half * 128 + l5 * 4;         // bf16 column of this lane (4 cols)

    const unsigned short* Ub = U + (size_t)b * NN * 256;
    size_t row = (size_t)b * NN + i;

    int deg = cnt[i];                     // per-lane (2 addrs/wave)
    int m = min(deg, CAP);
    const unsigned* lp = (const unsigned*)(adjb + (size_t)i * CAP);

    // independent streams issued up front
    const unsigned* ZbP = (const unsigned*)Out;
    u32x2 zz = __builtin_nontemporal_load((const u32x2*)&ZbP[row * 256 + 128 + (cu >> 1)]);
    float4 vs = *(const float4*)&bs[cu];
    float4 vn = *(const float4*)&bn[cu];
    u32x2 sv = *(const u32x2*)(Ub + (size_t)i * 256 + cu);   // self row

    float a0 = asf(sv[0] << 16), a1 = asf(sv[0] & 0xffff0000u);
    float a2 = asf(sv[1] << 16), a3 = asf(sv[1] & 0xffff0000u);

    int p = 0;
    for (; p + 16 <= m; p += 16) {        // per-lane cond: at most 2-way divergence
        unsigned w[8];
#pragma unroll
        for (int t = 0; t < 8; t++) w[t] = lp[(p >> 1) + t];
        u32x2 v[16];
#pragma unroll
        for (int t = 0; t < 8; t++) {
            unsigned j0 = w[t] & 0xffffu;
            unsigned j1 = w[t] >> 16;
            v[2 * t + 0] = *(const u32x2*)(Ub + (size_t)j0 * 256 + cu);
            v[2 * t + 1] = *(const u32x2*)(Ub + (size_t)j1 * 256 + cu);
        }
#pragma unroll
        for (int t = 0; t < 16; t++) {
            a0 += asf(v[t][0] << 16); a1 += asf(v[t][0] & 0xffff0000u);
            a2 += asf(v[t][1] << 16); a3 += asf(v[t][1] & 0xffff0000u);
        }
    }
    for (; p + 4 <= m; p += 4) {
        unsigned w2[2];
        w2[0] = lp[(p >> 1) + 0];
        w2[1] = lp[(p >> 1) + 1];
        u32x2 v[4];
#pragma unroll
        for (int t = 0; t < 2; t++) {
            unsigned j0 = w2[t] & 0xffffu;
            unsigned j1 = w2[t] >> 16;
            v[2 * t + 0] = *(const u32x2*)(Ub + (size_t)j0 * 256 + cu);
            v[2 * t + 1] = *(const u32x2*)(Ub + (size_t)j1 * 256 + cu);
        }
#pragma unroll
        for (int t = 0; t < 4; t++) {
            a0 += asf(v[t][0] << 16); a1 += asf(v[t][0] & 0xffff0000u);
            a2 += asf(v[t][1] << 16); a3 += asf(v[t][1] & 0xffff0000u);
        }
    }
    const unsigned short* lst = adjb + (size_t)i * CAP;
    for (; p < m; p++) {
        unsigned j = lst[p];
        u32x2 v = *(const u32x2*)(Ub + (size_t)j * 256 + cu);
        a0 += asf(v[0] << 16); a1 += asf(v[0] & 0xffff0000u);
        a2 += asf(v[1] << 16); a3 += asf(v[1] & 0xffff0000u);
    }

    float z0 = bf2f((unsigned short)(zz[0] & 0xffff));
    float z1 = bf2f((unsigned short)(zz[0] >> 16));
    float z2 = bf2f((unsigned short)(zz[1] & 0xffff));
    float z3 = bf2f((unsigned short)(zz[1] >> 16));

    float s = 1.0f / (float)(1 + deg);
    float v0 = z0 + vs.x + vn.x + s * a0;
    float v1 = z1 + vs.y + vn.y + s * a1;
    float v2 = z2 + vs.z + vn.z + s * a2;
    float v3 = z3 + vs.w + vn.w + s * a3;

    f32x4 gout;
    gout[0] = gelu1(v0);
    gout[1] = gelu1(v1);
    gout[2] = gelu1(v2);
    gout[3] = gelu1(v3);
    __builtin_nontemporal_store(gout, (f32x4*)&Out[row * 256 + cu]);
}

// ---------------- launch ----------------

extern "C" void kernel_launch(void* const* d_in, const int* in_sizes, int n_in,
                              void* d_out, int out_size, void* d_ws, size_t ws_size,
                              hipStream_t stream) {
    const float* x   = (const float*)d_in[0];
    const int* ei    = (const int*)d_in[1];       // int32 (harness converts ints)
    const float* Ws  = (const float*)d_in[2];
    const float* bsv = (const float*)d_in[3];
    const float* Wn  = (const float*)d_in[4];
    const float* bnv = (const float*)d_in[5];
    float* out = (float*)d_out;

    char* ws = (char*)d_ws;
    size_t o = 0;
    unsigned short* U   = (unsigned short*)(ws + o); o += (size_t)MROWS * OUTC * 2;  // 16 MB
    unsigned short* Wt2 = (unsigned short*)(ws + o); o += (size_t)512 * 256 * 2;     // 256 KB
    int* cnt = (int*)(ws + o);  o += (size_t)NN * 4;                                  // 32 KB
    unsigned short* adjb = (unsigned short*)(ws + o); o += (size_t)NN * CAP * 2;     // 1.5 MB

    prep_w<<<64, 256, 0, stream>>>(Ws, Wn, Wt2, cnt);

    gemm_fill<<<768, 256, 0, stream>>>(x, Wt2, (unsigned short*)out, U, ei, cnt, adjb);

    agg_gelu<<<8192, 256, 0, stream>>>(U, cnt, adjb, bsv, bnv, out);
}

// Round 12
// 143.543 us; speedup vs baseline: 1.1535x; 1.1535x over previous
//
#include <hip/hip_runtime.h>
#include <math.h>

#define BB 4
#define NN 8192
#define CC 256
#define OUTC 256
#define EE 262144
#define MROWS (BB*NN)   /* 32768 */
#define CAP 96          /* adjacency bucket capacity; deg ~ Poisson(32) */

typedef __attribute__((ext_vector_type(8))) short short8;
typedef __attribute__((ext_vector_type(4))) short s16x4;
typedef __attribute__((ext_vector_type(4))) float f32x4;
typedef __attribute__((ext_vector_type(2))) unsigned int u32x2;
typedef __attribute__((ext_vector_type(4))) unsigned int u32x4;

__device__ inline unsigned short f2bf(float f) {
    union { float f; unsigned u; } a; a.f = f;
    unsigned u = a.u;
    u += 0x7fffu + ((u >> 16) & 1u);   // RNE
    return (unsigned short)(u >> 16);
}
__device__ inline float bf2f(unsigned short h) {
    union { unsigned u; float f; } a; a.u = ((unsigned)h) << 16;
    return a.f;
}
__device__ inline float asf(unsigned u) {
    union { unsigned u; float f; } a; a.u = u;
    return a.f;
}
__device__ inline float gelu1(float v) {
    // tanh-form GeLU; |err| < ~1e-3, far below bf16 noise (threshold 0.12)
    float t = v * (0.7978845608f + 0.0356774081f * v * v);
    float e = __expf(2.0f * t);
    float th = 1.0f - 2.0f / (e + 1.0f);
    return 0.5f * v * (1.0f + th);
}

// ---------------- kernel 1: W -> fragment-order swizzle + cnt zero ----------------

__global__ __launch_bounds__(256) void prep_w(const float* __restrict__ Ws,
                                              const float* __restrict__ Wn,
                                              unsigned short* __restrict__ Wt2,
                                              int* __restrict__ cnt) {
    int bi = blockIdx.x;
    int tid = threadIdx.x;
    if (bi >= 32) {
        cnt[(bi - 32) * 256 + tid] = 0;
        return;
    }
    __shared__ float tile[64][65];
    int kt = bi >> 3, nt = bi & 7;          // kt 0..3, nt 0..7
    int k0 = kt * 64, n0 = nt * 64;
    const float* W = (n0 < 256) ? Ws : Wn;
    int ncol = n0 & 255;
#pragma unroll
    for (int p = 0; p < 4; p++) {
        int krow = p * 16 + (tid >> 4);
        int col = (tid & 15) * 4;
        float4 v = *(const float4*)&W[(size_t)(k0 + krow) * 256 + ncol + col];
        tile[krow][col + 0] = v.x;
        tile[krow][col + 1] = v.y;
        tile[krow][col + 2] = v.z;
        tile[krow][col + 3] = v.w;
    }
    __syncthreads();
#pragma unroll
    for (int e = 0; e < 2; e++) {
        int idx = e * 256 + tid;            // 0..511
        int lane = idx & 63;
        int ni = (idx >> 6) & 3;
        int kkl = idx >> 8;                 // 0..1
        int kk = kt * 2 + kkl;
        int qrow = lane >> 4, fr = lane & 15;
        short8 t;
#pragma unroll
        for (int j = 0; j < 8; j++)
            t[j] = (short)f2bf(tile[kkl * 32 + qrow * 8 + j][ni * 16 + fr]);
        *(short8*)&Wt2[(size_t)(((nt * 8 + kk) * 4 + ni) * 512) + lane * 8] = t;
    }
}

// ---------------- kernel 2: edge bucket fill (blocks 0..255) + MFMA GEMM (256..767) --

#define APAD 8
#define ALD (256 + APAD)

__global__ __launch_bounds__(256, 2) void gemm_fill(const float* __restrict__ X,
                                                    const unsigned short* __restrict__ Wt2,
                                                    unsigned short* __restrict__ Zb,
                                                    unsigned short* __restrict__ U,
                                                    const int* __restrict__ ei,
                                                    int* __restrict__ cnt,
                                                    unsigned short* __restrict__ adjb) {
    __shared__ unsigned short sA[64 * ALD];
    int bi = blockIdx.x;
    int tid = threadIdx.x;

    if (bi < 256) {   // ---- edge bucket fill (leads the grid; overlaps GEMM) ----
        int e = bi * 256 + tid;
        for (; e < EE; e += 256 * 256) {
            int s = ei[e] & (NN - 1);
            int d = ei[EE + e] & (NN - 1);
            int slot = atomicAdd(&cnt[s], 1);
            if (slot < CAP) adjb[(size_t)s * CAP + slot] = (unsigned short)d;
        }
        return;
    }

    int wave = tid >> 6, lane = tid & 63;
    int row0 = (bi - 256) * 64;
    int qrow = lane >> 4;
    int fr = lane & 15;

    // stage A stripe (64x256 fp32 -> bf16), lane-contiguous: 16 req/instr
#pragma unroll
    for (int q = 0; q < 16; q++) {
        int f = q * 1024 + tid * 4;         // flat elem in 64x256
        int rr = f >> 8, k0 = f & 255;
        float4 v = *(const float4*)&X[(size_t)(row0 + rr) * 256 + k0];
        s16x4 t;
        t[0] = (short)f2bf(v.x); t[1] = (short)f2bf(v.y);
        t[2] = (short)f2bf(v.z); t[3] = (short)f2bf(v.w);
        *(s16x4*)&sA[rr * ALD + k0] = t;
    }
    __syncthreads();   // the only barrier

#pragma unroll 1
    for (int sp = 0; sp < 2; sp++) {
        int colbase = wave * 128 + sp * 64;         // global col in [0,512)
        int ct = wave * 2 + sp;                     // 64-col tile id
        const unsigned short* Bp = Wt2 + (size_t)ct * 8 * 4 * 512 + lane * 8;
        // frag (kk, ni) at Bp + (kk*4+ni)*512

        f32x4 acc[4][4];   // [ni][mi]
#pragma unroll
        for (int ni = 0; ni < 4; ni++)
#pragma unroll
            for (int mi = 0; mi < 4; mi++) acc[ni][mi] = (f32x4)0.0f;

        short8 bbuf[3][4];
#pragma unroll
        for (int ni = 0; ni < 4; ni++) {
            bbuf[0][ni] = *(const short8*)&Bp[(size_t)(0 * 4 + ni) * 512];
            bbuf[1][ni] = *(const short8*)&Bp[(size_t)(1 * 4 + ni) * 512];
        }

#pragma unroll
        for (int kk = 0; kk < 8; kk++) {
            if (kk < 6) {
#pragma unroll
                for (int ni = 0; ni < 4; ni++)
                    bbuf[(kk + 2) % 3][ni] =
                        *(const short8*)&Bp[(size_t)((kk + 2) * 4 + ni) * 512];
            }
            int ak = kk * 32 + qrow * 8;
            short8 af[4];
#pragma unroll
            for (int mi = 0; mi < 4; mi++)
                af[mi] = *(const short8*)&sA[(mi * 16 + fr) * ALD + ak];
            // OPERAND-SWAPPED: D' = (Wt-frag as A-op) x (X-frag as B-op) = C^T tile
#pragma unroll
            for (int ni = 0; ni < 4; ni++)
#pragma unroll
                for (int mi = 0; mi < 4; mi++)
                    acc[ni][mi] = __builtin_amdgcn_mfma_f32_16x16x32_bf16(
                        bbuf[kk % 3][ni], af[mi], acc[ni][mi], 0, 0, 0);
        }

        // epilogue: lane holds C[row = row0+mi*16+fr][cols colbase+ni*16+qrow*4 .. +3]
#pragma unroll
        for (int mi = 0; mi < 4; mi++) {
            size_t row = (size_t)(row0 + mi * 16 + fr);
#pragma unroll
            for (int ni = 0; ni < 4; ni++) {
                int col = colbase + ni * 16 + qrow * 4;
                s16x4 t;
                t[0] = (short)f2bf(acc[ni][mi][0]);
                t[1] = (short)f2bf(acc[ni][mi][1]);
                t[2] = (short)f2bf(acc[ni][mi][2]);
                t[3] = (short)f2bf(acc[ni][mi][3]);
                if (colbase < 256) *(s16x4*)&Zb[row * 512 + 256 + col] = t;  // d_out row tail
                else               *(s16x4*)&U[row * 256 + (col - 256)] = t;
            }
        }
    }
}

// ---------------- kernel 3: aggregate + bias + GeLU -------------------------------
// Model (r5=47.2, r6=51, r7=52.2, r10=58.9): time = rounds/wave x const-latency /
// resident-waves. r6/r7 (more overlap) and r10 (better residency, FETCH 42->29MB)
// didn't help -> the only unmoved term is ROUND COUNT (= deg = ~35). This version
// HALVES it: one row per wave (r5 grid, verified best), u32x4 16B/lane gathers --
// lanes 0-31 = neighbor j0's full 512B row, lanes 32-63 = j1's. One load = 2
// neighbors; rounds = ceil((m+1)/2) ~ 18. Degree wave-uniform -> no divergence.
// Odd m: pad slot clamps to self row i; self term pre-scaled by (1-(m&1)) in init.
// Final: 8 shfl_xor(32) combine even/odd halves; all 64 lanes store 4 cols each.

__global__ __launch_bounds__(256) void agg_gelu(const unsigned short* __restrict__ U,
                                                const int* __restrict__ cnt,
                                                const unsigned short* __restrict__ adjb,
                                                const float* __restrict__ bs,
                                                const float* __restrict__ bn,
                                                float* __restrict__ Out) {
    int r = blockIdx.x & 7;               // XCD-pin: b = r&3 (2 XCDs per batch)
    int q = blockIdx.x >> 3;              // 0..1023
    int b = r & 3;
    int g = ((r >> 2) << 10) + q;         // 0..2047
    int i = (g << 2) + (threadIdx.x >> 6);
    i = __builtin_amdgcn_readfirstlane(i);   // wave-uniform
    int lane = threadIdx.x & 63;
    int l5 = lane & 31;
    int sub = lane >> 5;                  // 0: even-slot neighbors, 1: odd-slot
    int cb = l5 * 8;                      // this lane's 8-col slice base
    int c_out = cb + sub * 4;             // this lane's 4 output cols

    const unsigned short* Ub = U + (size_t)b * NN * 256;
    size_t row = (size_t)b * NN + i;

    int deg = cnt[i];                     // broadcast load
    int m = min(deg, CAP);
    int P = m & 1;
    int K = (m + 1) >> 1;                 // pair rounds (incl. pad when m odd)
    const unsigned* lp = (const unsigned*)(adjb + (size_t)i * CAP);

    // first-level independent loads
    const unsigned* ZbP = (const unsigned*)Out;
    u32x2 zz = __builtin_nontemporal_load((const u32x2*)&ZbP[row * 256 + 128 + (c_out >> 1)]);
    float4 vs = *(const float4*)&bs[c_out];
    float4 vn = *(const float4*)&bn[c_out];
    u32x4 sv4 = *(const u32x4*)(Ub + (size_t)i * 256 + cb);   // self row slice

    // init: even half gets (1-P)*self (pad slot adds the other self copy when P=1)
    float a[8];
    unsigned smask = (sub == 0 && P == 0) ? 0xffffffffu : 0u;
#pragma unroll
    for (int d = 0; d < 4; d++) {
        unsigned x = sv4[d] & smask;
        a[2 * d]     = asf(x << 16);
        a[2 * d + 1] = asf(x & 0xffff0000u);
    }

    int p = 0;
    for (; p + 8 <= K; p += 8) {          // 8 pairs = 16 neighbors per block
        unsigned w[8];
#pragma unroll
        for (int t = 0; t < 8; t++) w[t] = lp[p + t];
        u32x4 v4[8];
#pragma unroll
        for (int t = 0; t < 8; t++) {
            unsigned lo = w[t] & 0xffffu;
            unsigned hi = w[t] >> 16;
            hi = (2 * (p + t) + 1 < m) ? hi : (unsigned)i;   // clamp pad to self
            unsigned j = sub ? hi : lo;
            v4[t] = *(const u32x4*)(Ub + (size_t)j * 256 + cb);
        }
#pragma unroll
        for (int t = 0; t < 8; t++) {
#pragma unroll
            for (int d = 0; d < 4; d++) {
                a[2 * d]     += asf(v4[t][d] << 16);
                a[2 * d + 1] += asf(v4[t][d] & 0xffff0000u);
            }
        }
    }
    for (; p < K; p++) {                  // tail pairs (uniform bound, no divergence)
        unsigned w = lp[p];
        unsigned lo = w & 0xffffu;
        unsigned hi = w >> 16;
        hi = (2 * p + 1 < m) ? hi : (unsigned)i;
        unsigned j = sub ? hi : lo;
        u32x4 v4 = *(const u32x4*)(Ub + (size_t)j * 256 + cb);
#pragma unroll
        for (int d = 0; d < 4; d++) {
            a[2 * d]     += asf(v4[d] << 16);
            a[2 * d + 1] += asf(v4[d] & 0xffff0000u);
        }
    }

    // combine even/odd halves: lane l and l^32 hold partials for the SAME 8 cols
#pragma unroll
    for (int k = 0; k < 8; k++) a[k] += __shfl_xor(a[k], 32);

    // lane emits its 4 cols: sub==0 -> a[0..3], sub==1 -> a[4..7] (static idx + select)
    float r0 = sub ? a[4] : a[0];
    float r1 = sub ? a[5] : a[1];
    float r2 = sub ? a[6] : a[2];
    float r3 = sub ? a[7] : a[3];

    float z0 = bf2f((unsigned short)(zz[0] & 0xffff));
    float z1 = bf2f((unsigned short)(zz[0] >> 16));
    float z2 = bf2f((unsigned short)(zz[1] & 0xffff));
    float z3 = bf2f((unsigned short)(zz[1] >> 16));

    float s = 1.0f / (float)(1 + deg);
    float v0 = z0 + vs.x + vn.x + s * r0;
    float v1 = z1 + vs.y + vn.y + s * r1;
    float v2 = z2 + vs.z + vn.z + s * r2;
    float v3 = z3 + vs.w + vn.w + s * r3;

    f32x4 gout;
    gout[0] = gelu1(v0);
    gout[1] = gelu1(v1);
    gout[2] = gelu1(v2);
    gout[3] = gelu1(v3);
    __builtin_nontemporal_store(gout, (f32x4*)&Out[row * 256 + c_out]);
}

// ---------------- launch ----------------

extern "C" void kernel_launch(void* const* d_in, const int* in_sizes, int n_in,
                              void* d_out, int out_size, void* d_ws, size_t ws_size,
                              hipStream_t stream) {
    const float* x   = (const float*)d_in[0];
    const int* ei    = (const int*)d_in[1];       // int32 (harness converts ints)
    const float* Ws  = (const float*)d_in[2];
    const float* bsv = (const float*)d_in[3];
    const float* Wn  = (const float*)d_in[4];
    const float* bnv = (const float*)d_in[5];
    float* out = (float*)d_out;

    char* ws = (char*)d_ws;
    size_t o = 0;
    unsigned short* U   = (unsigned short*)(ws + o); o += (size_t)MROWS * OUTC * 2;  // 16 MB
    unsigned short* Wt2 = (unsigned short*)(ws + o); o += (size_t)512 * 256 * 2;     // 256 KB
    int* cnt = (int*)(ws + o);  o += (size_t)NN * 4;                                  // 32 KB
    unsigned short* adjb = (unsigned short*)(ws + o); o += (size_t)NN * CAP * 2;     // 1.5 MB

    prep_w<<<64, 256, 0, stream>>>(Ws, Wn, Wt2, cnt);

    gemm_fill<<<768, 256, 0, stream>>>(x, Wt2, (unsigned short*)out, U, ei, cnt, adjb);

    agg_gelu<<<8192, 256, 0, stream>>>(U, cnt, adjb, bsv, bnv, out);
}